// Round 4
// baseline (33.452 us; speedup 1.0000x reference)
//
#include <hip/hip_runtime.h>

typedef float f32x2 __attribute__((ext_vector_type(2)));

#define BB 4
#define CC 3
#define HH 1024
#define WW 1024
#define PAD 8
#define WP (WW + 2 * PAD)   // 1040

__global__ __launch_bounds__(256) void dpmerge_kernel(
    const float* __restrict__ image,   // (B,C,H,W)
    const float* __restrict__ depth,   // (B,H,W)
    float* __restrict__ out)           // left (B,C,H,W) then right (B,C,H,W)
{
    __shared__ __align__(16) float pl[WP];     // posL = s + d (bit-exact vs ref)
    __shared__ __align__(16) float pr[WP];     // posR = s - d
    __shared__ __align__(16) f32x2 s01[WP];    // channels 0,1 interleaved
    __shared__ __align__(16) float s2[WP];     // channel 2

    const int row = blockIdx.x;        // 0 .. B*H-1
    const int b   = row >> 10;
    const int h   = row & (HH - 1);
    const int tid = threadIdx.x;

    const size_t chStride = (size_t)HH * WW;
    const size_t imgBase  = ((size_t)b * CC) * chStride + (size_t)h * WW;

    // ---- stage ----
    {
        const float4 dv = reinterpret_cast<const float4*>(depth + (size_t)row * WW)[tid];
        const int   sbi = 4 * tid;
        float4 a, r;
        a.x = (float)(sbi + 0) + dv.x;  r.x = (float)(sbi + 0) - dv.x;
        a.y = (float)(sbi + 1) + dv.y;  r.y = (float)(sbi + 1) - dv.y;
        a.z = (float)(sbi + 2) + dv.z;  r.z = (float)(sbi + 2) - dv.z;
        a.w = (float)(sbi + 3) + dv.w;  r.w = (float)(sbi + 3) - dv.w;
        reinterpret_cast<float4*>(pl + PAD)[tid] = a;
        reinterpret_cast<float4*>(pr + PAD)[tid] = r;

        const float4 v0 = reinterpret_cast<const float4*>(image + imgBase)[tid];
        const float4 v1 = reinterpret_cast<const float4*>(image + imgBase + chStride)[tid];
        const float4 v2 = reinterpret_cast<const float4*>(image + imgBase + 2 * chStride)[tid];
        float4 w0, w1;
        w0.x = v0.x; w0.y = v1.x; w0.z = v0.y; w0.w = v1.y;
        w1.x = v0.z; w1.y = v1.z; w1.z = v0.w; w1.w = v1.w;
        reinterpret_cast<float4*>(reinterpret_cast<float*>(s01 + PAD))[2 * tid]     = w0;
        reinterpret_cast<float4*>(reinterpret_cast<float*>(s01 + PAD))[2 * tid + 1] = w1;
        reinterpret_cast<float4*>(s2 + PAD)[tid] = v2;
    }
    if (tid < 2 * PAD) {
        const int idx = (tid < PAD) ? tid : (WW + tid);  // 0..7 and 1032..1039
        pl[idx] = 1e30f;                 // poison -> weight 0 naturally
        pr[idx] = 1e30f;
        s01[idx].x = 0.f; s01[idx].y = 0.f;
        s2[idx] = 0.f;
    }
    __syncthreads();

    const size_t NV = (size_t)BB * CC * chStride;   // right-view offset in out
    const int    x0 = 4 * tid;

    const float4* PL  = reinterpret_cast<const float4*>(pl);
    const float4* PR  = reinterpret_cast<const float4*>(pr);
    const float4* S2  = reinterpret_cast<const float4*>(s2);
    const float4* S01 = reinterpret_cast<const float4*>(s01);

    // Load a 12-source window: pos (3 chunks), img01 (6 chunks -> f32x2[12]),
    // img2 (3 chunks).
#define LOADWIN(pwv, w01v, s2v, POS, posC, imgC)                                \
    {                                                                           \
        const float4 _p0 = (POS)[(posC)];                                       \
        const float4 _p1 = (POS)[(posC) + 1];                                   \
        const float4 _p2 = (POS)[(posC) + 2];                                   \
        pwv[0] = _p0.x; pwv[1]  = _p0.y; pwv[2]  = _p0.z; pwv[3]  = _p0.w;      \
        pwv[4] = _p1.x; pwv[5]  = _p1.y; pwv[6]  = _p1.z; pwv[7]  = _p1.w;      \
        pwv[8] = _p2.x; pwv[9]  = _p2.y; pwv[10] = _p2.z; pwv[11] = _p2.w;      \
        _Pragma("unroll")                                                       \
        for (int _c = 0; _c < 6; ++_c) {                                        \
            const float4 _v = S01[(imgC) + _c];                                 \
            w01v[2 * _c].x     = _v.x; w01v[2 * _c].y     = _v.y;               \
            w01v[2 * _c + 1].x = _v.z; w01v[2 * _c + 1].y = _v.w;               \
        }                                                                       \
        const float4 _s0 = S2[(posC)];                                          \
        const float4 _s1 = S2[(posC) + 1];                                      \
        const float4 _s2 = S2[(posC) + 2];                                      \
        s2v[0] = _s0.x; s2v[1]  = _s0.y; s2v[2]  = _s0.z; s2v[3]  = _s0.w;      \
        s2v[4] = _s1.x; s2v[5]  = _s1.y; s2v[6]  = _s1.z; s2v[7]  = _s1.w;      \
        s2v[8] = _s2.x; s2v[9]  = _s2.y; s2v[10] = _s2.z; s2v[11] = _s2.w;      \
    }

#define COMPUTE_STORE(obase)                                                    \
    {                                                                           \
        float4 oc0, oc1, oc2;                                                   \
        float* o0 = &oc0.x; float* o1 = &oc1.x; float* o2 = &oc2.x;             \
        _Pragma("unroll")                                                       \
        for (int j = 0; j < 4; ++j) {                                           \
            const float xf = (float)(x0 + j);                                   \
            f32x2 acc; acc.x = 0.f; acc.y = 0.f;                                \
            float a2 = 0.f, cl = 0.f;                                           \
            _Pragma("unroll")                                                   \
            for (int i = 0; i < 9; ++i) {                                       \
                const int   u  = j + i;                                         \
                const float t  = pw[u] - xf;                                    \
                const float wt = fmaxf(1.0f - fabsf(t), 0.0f);                  \
                f32x2 wt2; wt2.x = wt; wt2.y = wt;                              \
                acc = __builtin_elementwise_fma(w01[u], wt2, acc);              \
                a2  = fmaf(s2w[u], wt, a2);                                     \
                cl += wt;                                                       \
            }                                                                   \
            const float inv = __builtin_amdgcn_rcpf(fmaxf(cl, 1e-30f));         \
            o0[j] = acc.x * inv;                                                \
            o1[j] = acc.y * inv;                                                \
            o2[j] = a2 * inv;                                                   \
        }                                                                       \
        *reinterpret_cast<float4*>(out + (obase) + x0)                = oc0;    \
        *reinterpret_cast<float4*>(out + (obase) + chStride + x0)     = oc1;    \
        *reinterpret_cast<float4*>(out + (obase) + 2 * chStride + x0) = oc2;    \
    }

    // ===== LEFT view: sources s in [x0-8, x0+3] (padded idx 4tid..4tid+11) ===
    {
        float pw[12], s2w[12];
        f32x2 w01[12];
        LOADWIN(pw, w01, s2w, PL, tid, 2 * tid);
        COMPUTE_STORE(imgBase);
    }

    // ===== RIGHT view: sources s in [x0, x0+11] (padded idx 4tid+8..4tid+19) =
    {
        float pw[12], s2w[12];
        f32x2 w01[12];
        LOADWIN(pw, w01, s2w, PR, tid + 2, 2 * tid + 4);
        COMPUTE_STORE(NV + imgBase);
    }
#undef LOADWIN
#undef COMPUTE_STORE
}

extern "C" void kernel_launch(void* const* d_in, const int* in_sizes, int n_in,
                              void* d_out, int out_size, void* d_ws, size_t ws_size,
                              hipStream_t stream) {
    const float* image = (const float*)d_in[0];
    const float* depth = (const float*)d_in[1];
    float* out = (float*)d_out;
    (void)in_sizes; (void)n_in; (void)out_size; (void)d_ws; (void)ws_size;

    dim3 grid(BB * HH);   // 4096 rows
    dim3 block(256);
    hipLaunchKernelGGL(dpmerge_kernel, grid, block, 0, stream, image, depth, out);
}

// Round 5
// 33.107 us; speedup vs baseline: 1.0104x; 1.0104x over previous
//
#include <hip/hip_runtime.h>

#define BB 4
#define CC 3
#define HH 1024
#define WW 1024
#define NCHUNK (WW / 4)   // 256 float4 chunks per row

__global__ __launch_bounds__(256) void dpmerge_kernel(
    const float* __restrict__ image,   // (B,C,H,W)
    const float* __restrict__ depth,   // (B,H,W)
    float* __restrict__ out)           // left (B,C,H,W) then right (B,C,H,W)
{
    const int row = blockIdx.x;        // 0 .. B*H-1
    const int b   = row >> 10;
    const int h   = row & (HH - 1);
    const int tid = threadIdx.x;
    const int x0  = 4 * tid;           // this thread's 4 output pixels x0..x0+3

    const size_t chStride = (size_t)HH * WW;
    const size_t imgBase  = ((size_t)b * CC) * chStride + (size_t)h * WW;
    const size_t NV       = (size_t)BB * CC * chStride;   // right-view offset

    // Union source window for both views: s in [x0-8, x0+11] -> chunks tid-2..tid+2
    int ci[5];
#pragma unroll
    for (int i = 0; i < 5; ++i) {
        int c = tid - 2 + i;
        c = c < 0 ? 0 : (c > NCHUNK - 1 ? NCHUNK - 1 : c);
        ci[i] = c;
    }

    const float4* Drow = reinterpret_cast<const float4*>(depth + (size_t)row * WW);
    const float4* I0   = reinterpret_cast<const float4*>(image + imgBase);
    const float4* I1   = reinterpret_cast<const float4*>(image + imgBase + chStride);
    const float4* I2   = reinterpret_cast<const float4*>(image + imgBase + 2 * chStride);

    float dw[20], im0[20], im1[20], im2[20];
#pragma unroll
    for (int i = 0; i < 5; ++i) {
        const float4 dv = Drow[ci[i]];
        const float4 v0 = I0[ci[i]];
        const float4 v1 = I1[ci[i]];
        const float4 v2 = I2[ci[i]];
        dw [4*i+0] = dv.x; dw [4*i+1] = dv.y; dw [4*i+2] = dv.z; dw [4*i+3] = dv.w;
        im0[4*i+0] = v0.x; im0[4*i+1] = v0.y; im0[4*i+2] = v0.z; im0[4*i+3] = v0.w;
        im1[4*i+0] = v1.x; im1[4*i+1] = v1.y; im1[4*i+2] = v1.z; im1[4*i+3] = v1.w;
        im2[4*i+0] = v2.x; im2[4*i+1] = v2.y; im2[4*i+2] = v2.z; im2[4*i+3] = v2.w;
    }

    // Poison depth for out-of-range sources: weight becomes exactly 0.
    // Window element i corresponds to s = x0-8+i.
#pragma unroll
    for (int i = 0; i < 8; ++i)   // s<0 possible only for tid<2
        if (x0 - 8 + i < 0) dw[i] = 1e30f;
#pragma unroll
    for (int i = 12; i < 20; ++i) // s>=W possible only for tid>=253
        if (x0 - 8 + i >= WW) dw[i] = 1e30f;

    // pos arrays, bit-identical to reference: fl(float(s) +- d)
    const float xb = (float)x0;
    float posL[12], posR[12];
#pragma unroll
    for (int i = 0; i < 12; ++i)   // s = x0-8+i, left view needs s in [x0-8, x0+3]
        posL[i] = (xb + (float)(i - 8)) + dw[i];
#pragma unroll
    for (int j = 0; j < 12; ++j)   // s = x0+j, right view needs s in [x0, x0+11]
        posR[j] = (xb + (float)j) - dw[8 + j];

    // ===== LEFT view: pixel x0+j gathers s in [x-8, x] -> window idx u=j..j+8
    {
        float4 oc0, oc1, oc2;
        float* o0 = &oc0.x; float* o1 = &oc1.x; float* o2 = &oc2.x;
#pragma unroll
        for (int j = 0; j < 4; ++j) {
            const float xf = xb + (float)j;
            float cl = 0.f, a0 = 0.f, a1 = 0.f, a2 = 0.f;
#pragma unroll
            for (int i = 0; i < 9; ++i) {
                const int   u  = j + i;
                const float t  = posL[u] - xf;
                const float wt = fmaxf(1.0f - fabsf(t), 0.0f);
                cl += wt;
                a0 = fmaf(im0[u], wt, a0);
                a1 = fmaf(im1[u], wt, a1);
                a2 = fmaf(im2[u], wt, a2);
            }
            const float inv = __builtin_amdgcn_rcpf(fmaxf(cl, 1e-30f));
            o0[j] = a0 * inv;
            o1[j] = a1 * inv;
            o2[j] = a2 * inv;
        }
        *reinterpret_cast<float4*>(out + imgBase + x0)                = oc0;
        *reinterpret_cast<float4*>(out + imgBase + chStride + x0)     = oc1;
        *reinterpret_cast<float4*>(out + imgBase + 2 * chStride + x0) = oc2;
    }

    // ===== RIGHT view: pixel x0+j gathers s in [x, x+8] -> window idx u=j+8..j+16
    {
        float4 oc0, oc1, oc2;
        float* o0 = &oc0.x; float* o1 = &oc1.x; float* o2 = &oc2.x;
#pragma unroll
        for (int j = 0; j < 4; ++j) {
            const float xf = xb + (float)j;
            float cr = 0.f, a0 = 0.f, a1 = 0.f, a2 = 0.f;
#pragma unroll
            for (int i = 0; i < 9; ++i) {
                const int   u  = j + 8 + i;   // image window idx, s = x0+j+i
                const float t  = posR[j + i] - xf;
                const float wt = fmaxf(1.0f - fabsf(t), 0.0f);
                cr += wt;
                a0 = fmaf(im0[u], wt, a0);
                a1 = fmaf(im1[u], wt, a1);
                a2 = fmaf(im2[u], wt, a2);
            }
            const float inv = __builtin_amdgcn_rcpf(fmaxf(cr, 1e-30f));
            o0[j] = a0 * inv;
            o1[j] = a1 * inv;
            o2[j] = a2 * inv;
        }
        *reinterpret_cast<float4*>(out + NV + imgBase + x0)                = oc0;
        *reinterpret_cast<float4*>(out + NV + imgBase + chStride + x0)     = oc1;
        *reinterpret_cast<float4*>(out + NV + imgBase + 2 * chStride + x0) = oc2;
    }
}

extern "C" void kernel_launch(void* const* d_in, const int* in_sizes, int n_in,
                              void* d_out, int out_size, void* d_ws, size_t ws_size,
                              hipStream_t stream) {
    const float* image = (const float*)d_in[0];
    const float* depth = (const float*)d_in[1];
    float* out = (float*)d_out;
    (void)in_sizes; (void)n_in; (void)out_size; (void)d_ws; (void)ws_size;

    dim3 grid(BB * HH);   // 4096 rows
    dim3 block(256);
    hipLaunchKernelGGL(dpmerge_kernel, grid, block, 0, stream, image, depth, out);
}

// Round 7
// 32.508 us; speedup vs baseline: 1.0290x; 1.0184x over previous
//
#include <hip/hip_runtime.h>

typedef float f32x4 __attribute__((ext_vector_type(4)));

#define BB 4
#define CC 3
#define HH 1024
#define WW 1024
#define NCHUNK (WW / 4)   // 256 float4 chunks per row

__global__ __launch_bounds__(256, 5) void dpmerge_kernel(
    const float* __restrict__ image,   // (B,C,H,W)
    const float* __restrict__ depth,   // (B,H,W)
    float* __restrict__ out)           // left (B,C,H,W) then right (B,C,H,W)
{
    const int row = blockIdx.x;        // 0 .. B*H-1
    const int b   = row >> 10;
    const int h   = row & (HH - 1);
    const int tid = threadIdx.x;
    const int x0  = 4 * tid;           // this thread's 4 output pixels
    const float xb = (float)x0;

    const size_t chStride = (size_t)HH * WW;
    const size_t imgBase  = ((size_t)b * CC) * chStride + (size_t)h * WW;
    const size_t NV       = (size_t)BB * CC * chStride;   // right-view offset

    const f32x4* Drow = reinterpret_cast<const f32x4*>(depth + (size_t)row * WW);
    const f32x4* I0   = reinterpret_cast<const f32x4*>(image + imgBase);
    const f32x4* I1   = reinterpret_cast<const f32x4*>(image + imgBase + chStride);
    const f32x4* I2   = reinterpret_cast<const f32x4*>(image + imgBase + 2 * chStride);

#define LOADC(arr, SRC, c, i)                                                   \
    {                                                                           \
        const f32x4 _v = (SRC)[c];                                              \
        arr[4*(i)+0] = _v.x; arr[4*(i)+1] = _v.y;                               \
        arr[4*(i)+2] = _v.z; arr[4*(i)+3] = _v.w;                               \
    }

#define COMPUTE_STORE(obase)                                                    \
    {                                                                           \
        f32x4 oc0, oc1, oc2;                                                    \
        _Pragma("unroll")                                                       \
        for (int j = 0; j < 4; ++j) {                                           \
            const float xf = xb + (float)j;                                     \
            float cw = 0.f, a0 = 0.f, a1 = 0.f, a2 = 0.f;                       \
            _Pragma("unroll")                                                   \
            for (int i = 0; i < 9; ++i) {                                       \
                const int   u  = j + i;                                         \
                const float t  = pos[u] - xf;                                   \
                const float wt = fmaxf(1.0f - fabsf(t), 0.0f);                  \
                cw += wt;                                                       \
                a0 = fmaf(im0[u], wt, a0);                                      \
                a1 = fmaf(im1[u], wt, a1);                                      \
                a2 = fmaf(im2[u], wt, a2);                                      \
            }                                                                   \
            const float inv = __builtin_amdgcn_rcpf(fmaxf(cw, 1e-30f));         \
            oc0[j] = a0 * inv;                                                  \
            oc1[j] = a1 * inv;                                                  \
            oc2[j] = a2 * inv;                                                  \
        }                                                                       \
        __builtin_nontemporal_store(oc0,                                        \
            reinterpret_cast<f32x4*>(out + (obase) + x0));                      \
        __builtin_nontemporal_store(oc1,                                        \
            reinterpret_cast<f32x4*>(out + (obase) + chStride + x0));           \
        __builtin_nontemporal_store(oc2,                                        \
            reinterpret_cast<f32x4*>(out + (obase) + 2 * chStride + x0));       \
    }

    // ======= LEFT view: sources s in [x0-8, x0+3] = chunks tid-2..tid =======
    {
        float dw[12], im0[12], im1[12], im2[12];
#pragma unroll
        for (int i = 0; i < 3; ++i) {
            int c = tid - 2 + i;
            c = c < 0 ? 0 : c;
            LOADC(dw,  Drow, c, i);
            LOADC(im0, I0,   c, i);
            LOADC(im1, I1,   c, i);
            LOADC(im2, I2,   c, i);
        }
        if (x0 < 8) {                       // lanes tid 0,1 only
#pragma unroll
            for (int u = 0; u < 8; ++u)
                if (x0 - 8 + u < 0) dw[u] = 1e30f;   // s<0 -> weight 0
        }
        float pos[12];
#pragma unroll
        for (int u = 0; u < 12; ++u)        // s = x0-8+u, pos = fl(s) + d
            pos[u] = (xb + (float)(u - 8)) + dw[u];

        COMPUTE_STORE(imgBase);
    }

    // ======= RIGHT view: sources s in [x0, x0+11] = chunks tid..tid+2 =======
    {
        float dw[12], im0[12], im1[12], im2[12];
#pragma unroll
        for (int i = 0; i < 3; ++i) {
            int c = tid + i;
            c = c > NCHUNK - 1 ? NCHUNK - 1 : c;
            LOADC(dw,  Drow, c, i);
            LOADC(im0, I0,   c, i);
            LOADC(im1, I1,   c, i);
            LOADC(im2, I2,   c, i);
        }
        if (x0 + 11 >= WW) {                // lanes tid 254,255 only
#pragma unroll
            for (int u = 4; u < 12; ++u)
                if (x0 + u >= WW) dw[u] = 1e30f;     // s>=W -> weight 0
        }
        float pos[12];
#pragma unroll
        for (int u = 0; u < 12; ++u)        // s = x0+u, pos = fl(s) - d
            pos[u] = (xb + (float)u) - dw[u];

        COMPUTE_STORE(NV + imgBase);
    }
#undef LOADC
#undef COMPUTE_STORE
}

extern "C" void kernel_launch(void* const* d_in, const int* in_sizes, int n_in,
                              void* d_out, int out_size, void* d_ws, size_t ws_size,
                              hipStream_t stream) {
    const float* image = (const float*)d_in[0];
    const float* depth = (const float*)d_in[1];
    float* out = (float*)d_out;
    (void)in_sizes; (void)n_in; (void)out_size; (void)d_ws; (void)ws_size;

    dim3 grid(BB * HH);   // 4096 rows
    dim3 block(256);
    hipLaunchKernelGGL(dpmerge_kernel, grid, block, 0, stream, image, depth, out);
}